// Round 5
// baseline (262.007 us; speedup 1.0000x reference)
//
#include <hip/hip_runtime.h>
#include <hip/hip_bf16.h>

#define HSEQ 16777216   // 512*32*1024
#define NH 1024

typedef __attribute__((ext_vector_type(8))) short bf16x8;
typedef __attribute__((ext_vector_type(4))) float f32x4;

__device__ __forceinline__ unsigned short f2bf(float f) {
  unsigned u = __builtin_bit_cast(unsigned, f);
  u += 0x7fffu + ((u >> 16) & 1u);
  return (unsigned short)(u >> 16);
}

// Fused fp32->bf16 conversion: x (blocks 0-2047) + 4 gate weights (blocks 2048-3071).
__global__ __launch_bounds__(256) void cvt_all(
    const float* __restrict__ x,
    const float* __restrict__ wi, const float* __restrict__ wf,
    const float* __restrict__ wo, const float* __restrict__ wg,
    unsigned short* __restrict__ xb, unsigned short* __restrict__ wb) {
  int bid = blockIdx.x;
  const float* src; unsigned short* dst; int base, iters;
  if (bid < 2048) {
    src = x; dst = xb; base = bid * 8192; iters = 8;
  } else {
    int g = bid - 2048; int ws = g >> 8; int blk = g & 255;
    src = (ws == 0) ? wi : (ws == 1) ? wf : (ws == 2) ? wo : wg;
    dst = wb + ws * 1048576; base = blk * 4096; iters = 4;
  }
  int t = threadIdx.x;
  for (int i = 0; i < iters; ++i) {
    int idx = base + i * 1024 + t * 4;
    float4 v = *reinterpret_cast<const float4*>(src + idx);
    ushort4 o;
    o.x = f2bf(v.x); o.y = f2bf(v.y); o.z = f2bf(v.z); o.w = f2bf(v.w);
    *reinterpret_cast<ushort4*>(dst + idx) = o;
  }
}

// hz[g][b][h] = h0[b,:]·w_h[g][h,:] + b_i[g][h] + b_h[g][h]
__global__ __launch_bounds__(256) void hz_kernel(
    const float* __restrict__ h0,
    const float* __restrict__ wh_i, const float* __restrict__ wh_f,
    const float* __restrict__ wh_o, const float* __restrict__ wh_g,
    const float* __restrict__ bi_i, const float* __restrict__ bh_i,
    const float* __restrict__ bi_f, const float* __restrict__ bh_f,
    const float* __restrict__ bi_o, const float* __restrict__ bh_o,
    const float* __restrict__ bi_g, const float* __restrict__ bh_g,
    float* __restrict__ hz) {
  __shared__ float ws[8 * 1024];
  int g = blockIdx.x >> 7;
  int hb = blockIdx.x & 127;
  const float* wh = (g == 0) ? wh_i : (g == 1) ? wh_f : (g == 2) ? wh_o : wh_g;
  const float* bi = (g == 0) ? bi_i : (g == 1) ? bi_f : (g == 2) ? bi_o : bi_g;
  const float* bh = (g == 0) ? bh_i : (g == 1) ? bh_f : (g == 2) ? bh_o : bh_g;
  int tid = threadIdx.x;
  const float4* wsrc = reinterpret_cast<const float4*>(wh + hb * 8 * 1024);
  float4* wdst = reinterpret_cast<float4*>(ws);
  for (int i = tid; i < 2048; i += 256) wdst[i] = wsrc[i];
  __syncthreads();
  int b = tid & 31;
  int hh = tid >> 5;
  const float4* hv = reinterpret_cast<const float4*>(h0 + b * NH);
  const float4* wv = reinterpret_cast<const float4*>(ws + hh * NH);
  float acc = 0.f;
  for (int k = 0; k < 256; ++k) {
    float4 a = hv[k], w4 = wv[k];
    acc += a.x * w4.x + a.y * w4.y + a.z * w4.z + a.w * w4.w;
  }
  int h = hb * 8 + hh;
  hz[g * (32 * NH) + b * NH + h] = acc + bi[h] + bh[h];
}

__device__ __forceinline__ void load_lds16(const void* gsrc, void* lds) {
  __builtin_amdgcn_global_load_lds(
      (const __attribute__((address_space(1))) unsigned int*)gsrc,
      (__attribute__((address_space(3))) unsigned int*)lds, 16, 0, 0);
}

// 256x256 8-phase GEMM, register-double-buffered fragments (ds_reads one phase
// ahead of their MFMA, read-once banking: 48 ds_read_b128/iter/wave), exactly
// one 16KB stage unit per phase, vmcnt(4) only at p2/p6 immediately before the
// phase barrier (cross-wave visibility), single barrier per phase.
// BN=256 = 4 gates x 64 h. BK=64, 2 K-tiles/iter, 8 iters.
__global__ __launch_bounds__(512, 2) void lstm_gemm8(
    const unsigned short* __restrict__ xb,   // [16384][1024] bf16
    const unsigned short* __restrict__ wb,   // [4][1024][1024] bf16 (i,f,o,g)
    const float* __restrict__ hz,            // [4][32][1024] f32
    const float* __restrict__ c0,            // [32][1024] f32
    float* __restrict__ out) {
  __shared__ unsigned short As[2][16384];    // [buf][256 rows][64 cols]
  __shared__ unsigned short Bs[2][16384];

  const int bid0 = blockIdx.x;                       // 1024 blocks
  const int bid = (bid0 & 7) * 128 + (bid0 >> 3);    // XCD swizzle (1024%8==0)
  const int ht = bid & 15;
  const int mt = bid >> 4;
  const int mBase = mt * 256;
  const int hBase = ht * 64;

  const int tid = threadIdx.x;
  const int lane = tid & 63;
  const int w = tid >> 6;
  const int wr = w >> 2;        // 0..1
  const int wc = w & 3;         // 0..3
  const int laneLow = lane & 15;
  const int lane4 = lane >> 4;  // 0..3
  const int lx = lane & 7;

  const int sRow = w * 8 + (lane >> 3);               // row within 64-row round
  const int sCol = ((lane & 7) ^ (lane >> 3)) * 8;    // inverse-swizzled col
  // 32-bit stage offsets (saddr + voffset form)
  const unsigned aStage = (unsigned)((mBase + sRow) * 1024 + sCol);
  const unsigned bStage = (unsigned)((hBase + sRow) * 1024 + sCol);

#define STAGE_A(buf, kt, h)                                                        \
  do {                                                                             \
    _Pragma("unroll") for (int r_ = 0; r_ < 2; ++r_) {                             \
      load_lds16(xb + aStage + (unsigned)(((h) * 128 + r_ * 64) * 1024 + (kt) * 64), \
                 &As[buf][(h) * 8192 + r_ * 4096 + w * 512]);                      \
    }                                                                              \
  } while (0)

#define STAGE_B(buf, kt, h)                                                        \
  do {                                                                             \
    _Pragma("unroll") for (int r_ = 0; r_ < 2; ++r_) {                             \
      load_lds16(wb + bStage + (unsigned)(((h) * 2 + r_) * 1048576 + (kt) * 64),   \
                 &Bs[buf][(h) * 8192 + r_ * 4096 + w * 512]);                      \
    }                                                                              \
  } while (0)

#define LDA(dst, buf, mh)                                                          \
  do {                                                                             \
    _Pragma("unroll") for (int mi = 0; mi < 4; ++mi)                               \
    _Pragma("unroll") for (int kk = 0; kk < 2; ++kk) {                             \
      int row_ = wr * 128 + (mh) * 64 + mi * 16 + laneLow;                         \
      int slot_ = (kk * 4 + lane4) ^ lx;                                           \
      dst[mi][kk] = *reinterpret_cast<const bf16x8*>(&As[buf][row_ * 64 + slot_ * 8]); \
    }                                                                              \
  } while (0)

#define LDB(dst, buf, qh)                                                          \
  do {                                                                             \
    _Pragma("unroll") for (int q = 0; q < 2; ++q)                                  \
    _Pragma("unroll") for (int kk = 0; kk < 2; ++kk) {                             \
      int row_ = ((qh) * 2 + q) * 64 + wc * 16 + laneLow;                          \
      int slot_ = (kk * 4 + lane4) ^ lx;                                           \
      dst[q][kk] = *reinterpret_cast<const bf16x8*>(&Bs[buf][row_ * 64 + slot_ * 8]); \
    }                                                                              \
  } while (0)

#define MFMA16(A, B, MH, QH)                                                       \
  do {                                                                             \
    __builtin_amdgcn_s_setprio(1);                                                 \
    _Pragma("unroll") for (int mi = 0; mi < 4; ++mi)                               \
    _Pragma("unroll") for (int q = 0; q < 2; ++q)                                  \
    _Pragma("unroll") for (int kk = 0; kk < 2; ++kk)                               \
      acc[(MH) * 4 + mi][(QH) * 2 + q] = __builtin_amdgcn_mfma_f32_16x16x32_bf16(  \
          A[mi][kk], B[q][kk], acc[(MH) * 4 + mi][(QH) * 2 + q], 0, 0, 0);         \
    __builtin_amdgcn_s_setprio(0);                                                 \
  } while (0)

#define BAR __builtin_amdgcn_s_barrier()
#define VM(n) asm volatile("s_waitcnt vmcnt(" #n ")" ::: "memory")

  f32x4 acc[8][4];
#pragma unroll
  for (int i = 0; i < 8; ++i)
#pragma unroll
    for (int j = 0; j < 4; ++j) acc[i][j] = (f32x4){0.f, 0.f, 0.f, 0.f};

  bf16x8 afX[4][2], afY[4][2], bqA[2][2], bqB[2][2];

  // Prologue: buf0 <- tile0 complete (B0,B1,A0,A1); buf1 <- tile1 (B0,B1,A0).
  // (buf1.A1 <- tile1 is staged at p0 of it=0.)
  STAGE_B(0, 0, 0); STAGE_B(0, 0, 1); STAGE_A(0, 0, 0); STAGE_A(0, 0, 1);
  STAGE_B(1, 1, 0); STAGE_B(1, 1, 1); STAGE_A(1, 1, 0);
  VM(0);
  BAR;
  LDB(bqA, 0, 0);   // buf0.B0  (consumed p0, p3)
  LDA(afX, 0, 0);   // buf0.mh0 (consumed p0, p1)

  for (int it = 0; it < 8; ++it) {
    const int tOdd = 2 * it + 1;                       // buf1 tile of this iter
    const int tA2 = (2 * it + 2 > 15) ? 15 : 2 * it + 2;
    const int tB2 = (2 * it + 3 > 15) ? 15 : 2 * it + 3;

    // p0: read bqB<-buf0.B1; stage buf1.A1<-tOdd; MFMA buf0 (mh0,B0)
    LDB(bqB, 0, 1);
    STAGE_A(1, tOdd, 1);
    MFMA16(afX, bqA, 0, 0);
    BAR;

    // p1: read afY<-buf0.mh1; stage buf0.B0<-tA2; MFMA buf0 (mh0,B1)
    LDA(afY, 0, 1);
    STAGE_B(0, tA2, 0);
    MFMA16(afX, bqB, 0, 1);
    BAR;

    // p2: stage buf0.B1<-tA2; MFMA buf0 (mh1,B1); vmcnt(4) covers buf1 tile tOdd
    STAGE_B(0, tA2, 1);
    MFMA16(afY, bqB, 1, 1);
    VM(4);
    BAR;

    // p3: read bqB<-buf1.B0, afX<-buf1.mh0; stage buf0.A0<-tA2; MFMA buf0 (mh1,B0)
    LDB(bqB, 1, 0);
    LDA(afX, 1, 0);
    STAGE_A(0, tA2, 0);
    MFMA16(afY, bqA, 1, 0);
    BAR;

    // p4: read bqA<-buf1.B1; stage buf0.A1<-tA2; MFMA buf1 (mh0,B0)
    LDB(bqA, 1, 1);
    STAGE_A(0, tA2, 1);
    MFMA16(afX, bqB, 0, 0);
    BAR;

    // p5: read afY<-buf1.mh1; stage buf1.B0<-tB2; MFMA buf1 (mh0,B1)
    LDA(afY, 1, 1);
    STAGE_B(1, tB2, 0);
    MFMA16(afX, bqA, 0, 1);
    BAR;

    // p6: stage buf1.B1<-tB2; MFMA buf1 (mh1,B1); vmcnt(4) covers buf0 tile tA2
    STAGE_B(1, tB2, 1);
    MFMA16(afY, bqA, 1, 1);
    VM(4);
    BAR;

    // p7: read bqA<-buf0.B0 (tA2), afX<-buf0.mh0 (tA2); stage buf1.A0<-tB2;
    //     MFMA buf1 (mh1,B0)
    LDB(bqA, 0, 0);
    LDA(afX, 0, 0);
    STAGE_A(1, tB2, 0);
    MFMA16(afY, bqB, 1, 0);
    BAR;
  }

  // Epilogue: combine 4 gates (thread-local), activations, f32 writes.
  const int b = mBase >> 9;  // uniform per block
  const int h = hBase + wc * 16 + laneLow;
  float hzv[4];
#pragma unroll
  for (int g = 0; g < 4; ++g) hzv[g] = hz[g * 32768 + b * NH + h];
  const float c0v = c0[b * NH + h];
#pragma unroll
  for (int mi16 = 0; mi16 < 8; ++mi16) {
#pragma unroll
    for (int r = 0; r < 4; ++r) {
      int m = mBase + wr * 128 + mi16 * 16 + lane4 * 4 + r;
      int t = m & 511;
      float zi = acc[mi16][0][r] + hzv[0];
      float zf = acc[mi16][1][r] + hzv[1];
      float zo = acc[mi16][2][r] + hzv[2];
      float zg = acc[mi16][3][r] + hzv[3];
      float iv = 1.f / (1.f + __expf(-zi));
      float fv = 1.f / (1.f + __expf(-zf));
      float ov = 1.f / (1.f + __expf(-zo));
      float gv = tanhf(zg);
      float cv = fv * c0v + iv * gv;
      float hval = ov * tanhf(cv);
      out[(size_t)t * 32768 + b * NH + h] = hval;
      if (t == 511) {
        out[HSEQ + b * NH + h] = hval;
        out[HSEQ + 32768 + b * NH + h] = cv;
      }
    }
  }
}

extern "C" void kernel_launch(void* const* d_in, const int* in_sizes, int n_in,
                              void* d_out, int out_size, void* d_ws, size_t ws_size,
                              hipStream_t stream) {
  const float* x    = (const float*)d_in[0];
  const float* h0   = (const float*)d_in[1];
  const float* c0   = (const float*)d_in[2];
  const float* w_ii = (const float*)d_in[3];
  const float* b_ii = (const float*)d_in[4];
  const float* w_hi = (const float*)d_in[5];
  const float* b_hi = (const float*)d_in[6];
  const float* w_if = (const float*)d_in[7];
  const float* b_if = (const float*)d_in[8];
  const float* w_hf = (const float*)d_in[9];
  const float* b_hf = (const float*)d_in[10];
  const float* w_io = (const float*)d_in[11];
  const float* b_io = (const float*)d_in[12];
  const float* w_ho = (const float*)d_in[13];
  const float* b_ho = (const float*)d_in[14];
  const float* w_ig = (const float*)d_in[15];
  const float* b_ig = (const float*)d_in[16];
  const float* w_hg = (const float*)d_in[17];
  const float* b_hg = (const float*)d_in[18];

  unsigned short* xb = (unsigned short*)d_ws;          // 16777216 bf16
  unsigned short* wb = xb + 16777216;                  // 4*1048576 bf16
  float* hz = (float*)(wb + 4 * 1048576);              // 4*32*1024 f32
  float* out = (float*)d_out;

  hipLaunchKernelGGL(cvt_all, dim3(3072), dim3(256), 0, stream,
                     x, w_ii, w_if, w_io, w_ig, xb, wb);
  hipLaunchKernelGGL(hz_kernel, dim3(512), dim3(256), 0, stream, h0,
                     w_hi, w_hf, w_ho, w_hg,
                     b_ii, b_hi, b_if, b_hf, b_io, b_ho, b_ig, b_hg, hz);
  hipLaunchKernelGGL(lstm_gemm8, dim3(1024), dim3(512), 0, stream, xb, wb, hz, c0, out);
}